// Round 3
// baseline (322.424 us; speedup 1.0000x reference)
//
#include <hip/hip_runtime.h>
#include <hip/hip_bf16.h>

// Problem constants
#define B_    1024
#define DIMC  64      // DIM
#define T_    255     // S-1 sequence steps
#define H_    128
#define CS_   500
#define S_    256

#define MROWS 16             // batch rows per block
#define NBLK  (B_ / MROWS)   // 64 blocks
#define NTHR  512            // 8 waves
#define TCH   8              // timesteps staged per chunk
#define XSTR  136            // padded LDS row stride (bf16 elems)

// LDS carve (bytes): x 2x34816 | h 2x4352 | idx 4096  = 82432
#define OFF_H   69632
#define OFF_IDX 78336
#define SMEMB   82432

typedef __attribute__((ext_vector_type(8))) short bf16x8;
typedef __attribute__((ext_vector_type(4))) float f32x4;

__device__ __forceinline__ unsigned short f2bf(float f) {
    unsigned int u = __builtin_bit_cast(unsigned int, f);
    return (unsigned short)((u + 0x7FFFu + ((u >> 16) & 1u)) >> 16);
}
__device__ __forceinline__ float fast_rcp(float x) { return __builtin_amdgcn_rcpf(x); }
__device__ __forceinline__ float sigm(float x)   { float e = __expf(-x); return fast_rcp(1.0f + e); }
__device__ __forceinline__ float tanh_f(float x) { float e = __expf(2.0f * x); return 1.0f - 2.0f * fast_rcp(1.0f + e); }
__device__ __forceinline__ float leaky(float x)  { return x > 0.0f ? x : 0.01f * x; }
__device__ __forceinline__ int   imin(int a, int b) { return a < b ? a : b; }
// Barrier WITHOUT vmcnt drain: keeps prefetch global loads in flight.
__device__ __forceinline__ void bar_lgkm() {
    asm volatile("s_waitcnt lgkmcnt(0)\n\ts_barrier" ::: "memory");
}

// Epilogue LDS layout (dword offsets into smem)
#define OW1 0        // W1 padded 64 x 129
#define OW2 8256     // W2 padded 32 x 65
#define OW3 10336    // W3 padded 16 x 33
#define OWL 10864    // W_last padded 64 x 81
#define OHF 16048    // h fp32, 16 x 128
#define OS1 18096    // s1 per wave 8 x 64
#define OS2 18608    // s2 per wave 8 x 32
#define OS3 18864    // s3 per wave 8 x 16
#define OSL 18992    // last per wave 8 x 64   (ends 19504 dw = 78016 B < OFF_IDX)

__global__ __launch_bounds__(NTHR, 2)
void gru_fused(const float* __restrict__ x, const int* __restrict__ snippet,
               const float* __restrict__ slist,
               const float* __restrict__ W_ih, const float* __restrict__ W_hh,
               const float* __restrict__ b_ih, const float* __restrict__ b_hh,
               const float* __restrict__ W1, const float* __restrict__ b1,
               const float* __restrict__ W2, const float* __restrict__ b2,
               const float* __restrict__ W3, const float* __restrict__ b3,
               const float* __restrict__ Wl, const float* __restrict__ bl,
               float* __restrict__ out)
{
    __shared__ __attribute__((aligned(16))) unsigned char smem[SMEMB];
    unsigned short* shx0 = (unsigned short*)smem;                       // [2][TCH*MROWS*XSTR]
    unsigned short* shh0 = (unsigned short*)(smem + OFF_H);             // [2][MROWS*XSTR]
    int*            sidx = (int*)(smem + OFF_IDX);                      // [MROWS*DIMC]

    const int tid   = threadIdx.x;
    const int bbase = blockIdx.x * MROWS;
    const int lane  = tid & 63;
    const int wv    = tid >> 6;
    const int l15   = lane & 15;
    const int l4    = lane >> 4;

    // ---- snippet indices, zero h buffer 0 ----
    for (int i = tid; i < MROWS * DIMC; i += NTHR) {
        int r = i >> 6, d = i & 63;
        sidx[i] = snippet[(bbase + r) * DIMC + d];
    }
    for (int i = tid; i < MROWS * XSTR; i += NTHR) shh0[i] = 0;

    // ---- weight B-fragments in registers (whole kernel) ----
    bf16x8 wih[3][4], whh[3][4];
    {
        const int g = (wv << 4) + l15;
#pragma unroll
        for (int gt = 0; gt < 3; ++gt) {
#pragma unroll
            for (int kb = 0; kb < 4; ++kb) {
                const float* p1 = W_ih + (size_t)(gt * 128 + g) * 128 + kb * 32 + (l4 << 3);
                const float* p2 = W_hh + (size_t)(gt * 128 + g) * 128 + kb * 32 + (l4 << 3);
                f32x4 a0, a1, c0, c1;
                __builtin_memcpy(&a0, p1, 16); __builtin_memcpy(&a1, p1 + 4, 16);
                __builtin_memcpy(&c0, p2, 16); __builtin_memcpy(&c1, p2 + 4, 16);
                bf16x8 a, c;
#pragma unroll
                for (int e = 0; e < 4; ++e) {
                    a[e]     = (short)f2bf(a0[e]); a[e + 4] = (short)f2bf(a1[e]);
                    c[e]     = (short)f2bf(c0[e]); c[e + 4] = (short)f2bf(c1[e]);
                }
                wih[gt][kb] = a; whh[gt][kb] = c;
            }
        }
    }
    const int jj = (wv << 4) + l15;
    const float bias_r = b_ih[jj]       + b_hh[jj];
    const float bias_z = b_ih[128 + jj] + b_hh[128 + jj];
    const float bxn    = b_ih[256 + jj];
    const float bhn    = b_hh[256 + jj];

    __syncthreads();   // sidx ready, h0 zeroed

    // ---- staging: 2 units/thread; unit = (row, even k0) covering k0,k0+1 ----
    int rowu[2], k0u[2], isx[2];
    const float* pa[2]; const float* pb[2];
#pragma unroll
    for (int un = 0; un < 2; ++un) {
        int u  = tid + un * NTHR;
        int r  = u >> 6;
        int k0 = (u & 63) << 1;
        rowu[un] = r; k0u[un] = k0;
        if (k0 < DIMC) {
            isx[un] = 1;
            pa[un] = x + ((size_t)(bbase + r) * DIMC + k0) * T_;
            pb[un] = pa[un] + T_;
        } else {
            isx[un] = 0;
            int d = k0 - DIMC;
            pa[un] = slist + ((size_t)d       * CS_ + sidx[(r << 6) + d])     * S_;
            pb[un] = slist + ((size_t)(d + 1) * CS_ + sidx[(r << 6) + d + 1]) * S_;
        }
    }

    f32x4 sa[2][2], sb[2][2];   // 8 timesteps x 2 k per thread

    auto issue = [&](int t0) {
#pragma unroll
        for (int un = 0; un < 2; ++un) {
            if (isx[un] && t0 + TCH - 1 > T_ - 1) {   // x tail clamp (t0 = 248 only)
#pragma unroll
                for (int g = 0; g < 2; ++g) {
                    f32x4 va, vb;
#pragma unroll
                    for (int e = 0; e < 4; ++e) {
                        int tt = imin(t0 + g * 4 + e, T_ - 1);
                        va[e] = pa[un][tt]; vb[e] = pb[un][tt];
                    }
                    sa[un][g] = va; sb[un][g] = vb;
                }
            } else {
#pragma unroll
                for (int g = 0; g < 2; ++g) {
                    f32x4 va, vb;
                    __builtin_memcpy(&va, pa[un] + t0 + g * 4, 16);
                    __builtin_memcpy(&vb, pb[un] + t0 + g * 4, 16);
                    sa[un][g] = va; sb[un][g] = vb;
                }
            }
        }
    };

    auto commit = [&](int buf) {
        unsigned short* dst = shx0 + buf * (TCH * MROWS * XSTR);
#pragma unroll
        for (int un = 0; un < 2; ++un) {
#pragma unroll
            for (int g = 0; g < 2; ++g) {
#pragma unroll
                for (int e = 0; e < 4; ++e) {
                    int t = g * 4 + e;
                    unsigned pk = (unsigned)f2bf(sa[un][g][e]) | ((unsigned)f2bf(sb[un][g][e]) << 16);
                    *(unsigned*)&dst[(t * MROWS + rowu[un]) * XSTR + k0u[un]] = pk;
                }
            }
        }
    };

    int cur = 0;
    float hprev[4] = {0.f, 0.f, 0.f, 0.f};
    const f32x4 Z = {0.f, 0.f, 0.f, 0.f};

    // xg phase: batch x-part of gates for nt steps (independent MFMAs, off critical path)
    auto xg_phase = [&](int buf, int tb, int nt, f32x4* xr, f32x4* xz, f32x4* xn) {
        const unsigned short* base = shx0 + buf * (TCH * MROWS * XSTR);
#pragma unroll
        for (int tt = 0; tt < 4; ++tt) {
            if (tt >= nt) break;
            const unsigned short* xp = base + ((tb + tt) * MROWS + l15) * XSTR + (l4 << 3);
            bf16x8 a[4];
#pragma unroll
            for (int kb = 0; kb < 4; ++kb) a[kb] = *(const bf16x8*)(xp + kb * 32);
            f32x4 r = Z, z = Z, n = Z;
#pragma unroll
            for (int kb = 0; kb < 4; ++kb) {
                r = __builtin_amdgcn_mfma_f32_16x16x32_bf16(a[kb], wih[0][kb], r, 0, 0, 0);
                z = __builtin_amdgcn_mfma_f32_16x16x32_bf16(a[kb], wih[1][kb], z, 0, 0, 0);
                n = __builtin_amdgcn_mfma_f32_16x16x32_bf16(a[kb], wih[2][kb], n, 0, 0, 0);
            }
            xr[tt] = r; xz[tt] = z; xn[tt] = n;
        }
    };

    // one recurrence step: h-MFMAs seeded with xg, gates, h-write, raw barrier
    auto recur = [&](f32x4 xr, f32x4 xz, f32x4 xn) {
        const unsigned short* hp = shh0 + cur * (MROWS * XSTR) + l15 * XSTR + (l4 << 3);
        bf16x8 h0 = *(const bf16x8*)(hp);
        bf16x8 h1 = *(const bf16x8*)(hp + 32);
        bf16x8 h2 = *(const bf16x8*)(hp + 64);
        bf16x8 h3 = *(const bf16x8*)(hp + 96);
        // split 2+2 chains to halve MFMA dependency depth
        f32x4 arA = __builtin_amdgcn_mfma_f32_16x16x32_bf16(h0, whh[0][0], xr, 0, 0, 0);
        f32x4 azA = __builtin_amdgcn_mfma_f32_16x16x32_bf16(h0, whh[1][0], xz, 0, 0, 0);
        f32x4 anA = __builtin_amdgcn_mfma_f32_16x16x32_bf16(h0, whh[2][0], Z,  0, 0, 0);
        f32x4 arB = __builtin_amdgcn_mfma_f32_16x16x32_bf16(h2, whh[0][2], Z,  0, 0, 0);
        f32x4 azB = __builtin_amdgcn_mfma_f32_16x16x32_bf16(h2, whh[1][2], Z,  0, 0, 0);
        f32x4 anB = __builtin_amdgcn_mfma_f32_16x16x32_bf16(h2, whh[2][2], Z,  0, 0, 0);
        arA = __builtin_amdgcn_mfma_f32_16x16x32_bf16(h1, whh[0][1], arA, 0, 0, 0);
        azA = __builtin_amdgcn_mfma_f32_16x16x32_bf16(h1, whh[1][1], azA, 0, 0, 0);
        anA = __builtin_amdgcn_mfma_f32_16x16x32_bf16(h1, whh[2][1], anA, 0, 0, 0);
        arB = __builtin_amdgcn_mfma_f32_16x16x32_bf16(h3, whh[0][3], arB, 0, 0, 0);
        azB = __builtin_amdgcn_mfma_f32_16x16x32_bf16(h3, whh[1][3], azB, 0, 0, 0);
        anB = __builtin_amdgcn_mfma_f32_16x16x32_bf16(h3, whh[2][3], anB, 0, 0, 0);
        unsigned short* hw = shh0 + (cur ^ 1) * (MROWS * XSTR);
#pragma unroll
        for (int q = 0; q < 4; ++q) {
            float r = sigm(arA[q] + arB[q] + bias_r);
            float z = sigm(azA[q] + azB[q] + bias_z);
            float n = tanh_f(xn[q] + bxn + r * (anA[q] + anB[q] + bhn));
            float hn = (1.0f - z) * n + z * hprev[q];
            hprev[q] = hn;
            hw[((l4 << 2) + q) * XSTR + jj] = f2bf(hn);
        }
        bar_lgkm();
        cur ^= 1;
    };

    // ---- prologue: stage chunk 0 ----
    issue(0);
    commit(0);
    __syncthreads();

    // ---- main: 31 full chunks of 8 steps (t = 0..247) ----
    for (int c = 0; c < 31; ++c) {
        issue((c + 1) * TCH);           // prefetch; raw barriers keep it in flight
        const int bx = c & 1;
        f32x4 xr[4], xz[4], xn[4];
        xg_phase(bx, 0, 4, xr, xz, xn);
#pragma unroll
        for (int tt = 0; tt < 4; ++tt) recur(xr[tt], xz[tt], xn[tt]);
        xg_phase(bx, 4, 4, xr, xz, xn);
#pragma unroll
        for (int tt = 0; tt < 4; ++tt) recur(xr[tt], xz[tt], xn[tt]);
        commit((c + 1) & 1);
        bar_lgkm();
    }
    // ---- tail chunk: 7 steps (t = 248..254), buffer 1 ----
    {
        f32x4 xr[4], xz[4], xn[4];
        xg_phase(1, 0, 4, xr, xz, xn);
#pragma unroll
        for (int tt = 0; tt < 4; ++tt) recur(xr[tt], xz[tt], xn[tt]);
        xg_phase(1, 4, 3, xr, xz, xn);
#pragma unroll
        for (int tt = 0; tt < 3; ++tt) recur(xr[tt], xz[tt], xn[tt]);
    }

    // ================= fused MLP epilogue (LDS-resident weights) =================
    float* wl = (float*)smem;   // recurrence x/h buffers dead; idx region (>=78336B) preserved

    for (int i = tid; i < 8192; i += NTHR) wl[OW1 + (i >> 7) * 129 + (i & 127)] = W1[i];
    for (int i = tid; i < 2048; i += NTHR) wl[OW2 + (i >> 6) * 65  + (i & 63)]  = W2[i];
    for (int i = tid; i < 512;  i += NTHR) wl[OW3 + (i >> 5) * 33  + (i & 31)]  = W3[i];
    for (int i = tid; i < 5120; i += NTHR) wl[OWL + (i / 80) * 81  + (i % 80)]  = Wl[i];
#pragma unroll
    for (int q = 0; q < 4; ++q) wl[OHF + ((l4 << 2) + q) * 128 + jj] = hprev[q];
    __syncthreads();

    for (int mloc = 0; mloc < 2; ++mloc) {
        const int m = (wv << 1) + mloc;
        {
            float s = b1[lane];
            const float* w = wl + OW1 + lane * 129;
            for (int k = 0; k < 128; ++k) s += wl[OHF + m * 128 + k] * w[k];
            wl[OS1 + wv * 64 + lane] = leaky(s);
        }
        __syncthreads();
        if (lane < 32) {
            float s = b2[lane];
            const float* w = wl + OW2 + lane * 65;
            for (int k = 0; k < 64; ++k) s += wl[OS1 + wv * 64 + k] * w[k];
            wl[OS2 + wv * 32 + lane] = leaky(s);
        } else {
            int d = lane - 32;
            wl[OSL + wv * 64 + d]      = slist[((size_t)d        * CS_ + sidx[(m << 6) + d])      * S_ + (S_ - 1)];
            wl[OSL + wv * 64 + d + 32] = slist[((size_t)(d + 32) * CS_ + sidx[(m << 6) + d + 32]) * S_ + (S_ - 1)];
        }
        __syncthreads();
        if (lane < 16) {
            float s = b3[lane];
            const float* w = wl + OW3 + lane * 33;
            for (int k = 0; k < 32; ++k) s += wl[OS2 + wv * 32 + k] * w[k];
            wl[OS3 + wv * 16 + lane] = leaky(s);
        }
        __syncthreads();
        {
            float s = bl[lane];
            const float* w = wl + OWL + lane * 81;
#pragma unroll
            for (int i = 0; i < 16; ++i) s += wl[OS3 + wv * 16 + i] * w[i];
            for (int d = 0; d < 64; ++d) s += wl[OSL + wv * 64 + d] * w[16 + d];
            out[(size_t)(bbase + m) * DIMC + lane] = leaky(s);
        }
        __syncthreads();
    }
}

extern "C" void kernel_launch(void* const* d_in, const int* in_sizes, int n_in,
                              void* d_out, int out_size, void* d_ws, size_t ws_size,
                              hipStream_t stream) {
    (void)in_sizes; (void)n_in; (void)out_size; (void)d_ws; (void)ws_size;
    const float* x       = (const float*)d_in[0];
    const int*   snippet = (const int*)  d_in[1];
    const float* slist   = (const float*)d_in[2];
    const float* W_ih    = (const float*)d_in[3];
    const float* W_hh    = (const float*)d_in[4];
    const float* b_ih    = (const float*)d_in[5];
    const float* b_hh    = (const float*)d_in[6];
    const float* W1      = (const float*)d_in[7];
    const float* b1      = (const float*)d_in[8];
    const float* W2      = (const float*)d_in[9];
    const float* b2      = (const float*)d_in[10];
    const float* W3      = (const float*)d_in[11];
    const float* b3      = (const float*)d_in[12];
    const float* Wl      = (const float*)d_in[13];
    const float* bl      = (const float*)d_in[14];
    float* out = (float*)d_out;

    hipLaunchKernelGGL(gru_fused, dim3(NBLK), dim3(NTHR), 0, stream,
                       x, snippet, slist, W_ih, W_hh, b_ih, b_hh,
                       W1, b1, W2, b2, W3, b3, Wl, bl, out);
}